// Round 5
// baseline (550.965 us; speedup 1.0000x reference)
//
#include <hip/hip_runtime.h>

typedef __bf16 bf16;
typedef __bf16 bf16x8 __attribute__((ext_vector_type(8)));
typedef float  f32x4  __attribute__((ext_vector_type(4)));

#define NSP 4096   // h*w
#define NCH 256    // channels
#define NB  8      // batch

// global(16B per lane) -> LDS at wave-uniform base + lane*16
static __device__ __forceinline__ void glds16(const bf16* g, bf16* l) {
  __builtin_amdgcn_global_load_lds(
      (const __attribute__((address_space(1))) unsigned int*)g,
      (__attribute__((address_space(3))) unsigned int*)l, 16, 0, 0);
}

// ---------------- k_prep: GN partial sums (blocks 0..511) + weight cvt ----
__global__ __launch_bounds__(256) void k_prep(const float* __restrict__ x,
    const float* __restrict__ wq, const float* __restrict__ wk,
    const float* __restrict__ wv, const float* __restrict__ wo,
    bf16* __restrict__ wbf, float2* __restrict__ part) {
  if (blockIdx.x < 512) {                       // GN stats: 64 bg * 8 seg
    int blk = blockIdx.x;
    int bg = blk >> 3, seg = blk & 7;
    const float4* p = (const float4*)(x + (size_t)bg * 131072 + seg * 16384);
    float s = 0.f, s2 = 0.f;
    for (int i = threadIdx.x; i < 4096; i += 256) {
      float4 v = p[i];
      s  += v.x + v.y + v.z + v.w;
      s2 += v.x*v.x + v.y*v.y + v.z*v.z + v.w*v.w;
    }
    for (int off = 1; off < 64; off <<= 1) {
      s  += __shfl_xor(s, off);
      s2 += __shfl_xor(s2, off);
    }
    __shared__ float a1[4], a2[4];
    int w = threadIdx.x >> 6, lane = threadIdx.x & 63;
    if (lane == 0) { a1[w] = s; a2[w] = s2; }
    __syncthreads();
    if (threadIdx.x == 0)
      part[blk] = make_float2(a1[0]+a1[1]+a1[2]+a1[3], a2[0]+a2[1]+a2[2]+a2[3]);
  } else {                                      // weight fp32->bf16
    int g = (blockIdx.x - 512) * 256 + threadIdx.x;   // 0..262143
    int m = g >> 16, idx = g & 65535;
    const float* src = (m == 0) ? wq : (m == 1) ? wk : (m == 2) ? wv : wo;
    float sc = (m == 0) ? 0.0625f : 1.0f;
    wbf[g] = (bf16)(src[idx] * sc);
  }
}

// ---------------- k1b: finalize stats --------------------------------------
__global__ __launch_bounds__(64) void k_gnstats2(const float2* __restrict__ part,
                                                 float* __restrict__ stats) {
  int bg = threadIdx.x;                         // 64
  float s = 0.f, s2 = 0.f;
  #pragma unroll
  for (int k = 0; k < 8; ++k) {
    float2 v = part[bg * 8 + k];
    s += v.x; s2 += v.y;
  }
  float mean = s * (1.f / 131072.f);
  float var  = s2 * (1.f / 131072.f) - mean * mean;
  stats[bg * 2]     = mean;
  stats[bg * 2 + 1] = rsqrtf(var + 1e-6f);
}

// ---------------- k2: GN apply + transpose -> hnT[b][n][c] bf16 -----------
__global__ __launch_bounds__(256) void k_gnapply(const float* __restrict__ x,
    const float* __restrict__ stats, const float* __restrict__ gsc,
    const float* __restrict__ gbi, bf16* __restrict__ hnT) {
  __shared__ float T[64][65];
  int blk = blockIdx.x;                         // 2048
  int b = blk >> 8, ct = (blk >> 6) & 3, it = blk & 63;
  int tid = threadIdx.x;
  #pragma unroll 4
  for (int p = 0; p < 16; ++p) {
    int cc = p * 4 + (tid >> 6), ii = tid & 63;
    int c = ct * 64 + cc;
    float mean = stats[(b * 8 + (c >> 5)) * 2];
    float rstd = stats[(b * 8 + (c >> 5)) * 2 + 1];
    float v = x[((size_t)b * NCH + c) * NSP + it * 64 + ii];
    T[cc][ii] = (v - mean) * rstd * gsc[c] + gbi[c];
  }
  __syncthreads();
  #pragma unroll 4
  for (int p = 0; p < 16; ++p) {
    int ii = p * 4 + (tid >> 6), cc = tid & 63;
    hnT[((size_t)b * NSP + it * 64 + ii) * NCH + ct * 64 + cc] = (bf16)T[cc][ii];
  }
}

// ---------------- k3: fused QKV: hn tile staged once in LDS ----------------
// 512 blocks; hn tile [64i][256c] in LDS, granule-swizzled g' = g ^ (i&7).
// q: qT[b][i][c].  k: kS pre-swizzled K tiles (granule cb ^ (j&7)) for the
// glds path.  v: vS PLAIN tiles (256c x 32j): granule g of row c holds
// j in {4g+t&3, 16+4g+(t>>2 ? ...)}: element t -> j = 4g + (t&3) + 16*(t>>2).
__global__ __launch_bounds__(256, 4) void k_qkv(const bf16* __restrict__ hnT,
    const bf16* __restrict__ wbf, const float* __restrict__ bq,
    const float* __restrict__ bk, const float* __restrict__ bv,
    bf16* __restrict__ qT, bf16* __restrict__ kS, bf16* __restrict__ vS) {
  __shared__ bf16 hnS[64 * 256];                // 32 KB
  const int b  = blockIdx.x >> 6;
  const int i0 = (blockIdx.x & 63) * 64;
  const int tid = threadIdx.x, w = tid >> 6, lane = tid & 63;
  const int li = lane & 15, qd = lane >> 4;

  #pragma unroll
  for (int p = 0; p < 8; ++p) {                 // stage + swizzle
    int idx = p * 256 + tid;
    int i = idx >> 5, g = idx & 31;
    bf16x8 v = *(const bf16x8*)(hnT + ((size_t)b * NSP + i0 + i) * NCH + g * 8);
    *(bf16x8*)(&hnS[i * 256 + (g ^ (i & 7)) * 8]) = v;
  }
  __syncthreads();

  #pragma unroll 1
  for (int pass = 0; pass < 2; ++pass) {        // 0: q, 1: k
    const bf16* W = wbf + (size_t)pass * 65536;
    f32x4 acc[16];
    #pragma unroll
    for (int t = 0; t < 16; ++t) acc[t] = (f32x4){0.f, 0.f, 0.f, 0.f};
    for (int kc = 0; kc < 8; ++kc) {
      bf16x8 hb[4];
      #pragma unroll
      for (int nt = 0; nt < 4; ++nt)
        hb[nt] = *(const bf16x8*)(&hnS[(nt * 16 + li) * 256 + ((kc * 4 + qd) ^ (li & 7)) * 8]);
      #pragma unroll
      for (int mt = 0; mt < 4; ++mt) {
        bf16x8 wf = *(const bf16x8*)(W + (size_t)(w * 64 + mt * 16 + li) * NCH + kc * 32 + qd * 8);
        #pragma unroll
        for (int nt = 0; nt < 4; ++nt)
          acc[mt * 4 + nt] = __builtin_amdgcn_mfma_f32_16x16x32_bf16(wf, hb[nt], acc[mt * 4 + nt], 0, 0, 0);
      }
    }
    if (pass == 0) {
      bf16* out = qT + ((size_t)b * NSP + i0) * NCH;
      #pragma unroll
      for (int mt = 0; mt < 4; ++mt) {
        float bb[4];
        #pragma unroll
        for (int r = 0; r < 4; ++r) bb[r] = bq[w * 64 + mt * 16 + qd * 4 + r] * 0.0625f;
        #pragma unroll
        for (int nt = 0; nt < 4; ++nt) {
          union { bf16 h[4]; uint2 u; } pk;
          #pragma unroll
          for (int r = 0; r < 4; ++r) pk.h[r] = (bf16)(acc[mt * 4 + nt][r] + bb[r]);
          *(uint2*)(out + (size_t)(nt * 16 + li) * NCH + w * 64 + mt * 16 + qd * 4) = pk.u;
        }
      }
    } else {
      #pragma unroll
      for (int mt = 0; mt < 4; ++mt) {
        float bb[4];
        #pragma unroll
        for (int r = 0; r < 4; ++r) bb[r] = bk[w * 64 + mt * 16 + qd * 4 + r];
        int cb = w * 8 + mt * 2 + (qd >> 1);
        #pragma unroll
        for (int nt = 0; nt < 4; ++nt) {
          int jloc = nt * 16 + li;
          size_t base = (size_t)b * 1048576 + (size_t)((i0 + jloc) >> 5) * 8192;
          int r32 = jloc & 31;
          union { bf16 h[4]; uint2 u; } pk;
          #pragma unroll
          for (int r = 0; r < 4; ++r) pk.h[r] = (bf16)(acc[mt * 4 + nt][r] + bb[r]);
          *(uint2*)(kS + base + r32 * 256 + (cb ^ (r32 & 7)) * 8 + (qd & 1) * 4) = pk.u;
        }
      }
    }
  }

  {  // v pass: D[m=j][n=co], A = hn rows(j), B = Wv rows(co)
    const bf16* W = wbf + 2ull * 65536;
    f32x4 acc[16];
    #pragma unroll
    for (int t = 0; t < 16; ++t) acc[t] = (f32x4){0.f, 0.f, 0.f, 0.f};
    for (int kc = 0; kc < 8; ++kc) {
      bf16x8 hb = *(const bf16x8*)(&hnS[(w * 16 + li) * 256 + ((kc * 4 + qd) ^ (li & 7)) * 8]);
      #pragma unroll
      for (int ct = 0; ct < 16; ++ct) {
        bf16x8 wf = *(const bf16x8*)(W + (size_t)(ct * 16 + li) * NCH + kc * 32 + qd * 8);
        acc[ct] = __builtin_amdgcn_mfma_f32_16x16x32_bf16(hb, wf, acc[ct], 0, 0, 0);
      }
    }
    int jloc = w * 16 + qd * 4;                  // + r over regs
    size_t base = (size_t)b * 1048576 + (size_t)((i0 + jloc) >> 5) * 8192;
    #pragma unroll
    for (int ct = 0; ct < 16; ++ct) {
      int co = ct * 16 + li;
      float bb = bv[co];
      union { bf16 h[4]; uint2 u; } pk;
      #pragma unroll
      for (int r = 0; r < 4; ++r) pk.h[r] = (bf16)(acc[ct][r] + bb);
      *(uint2*)(vS + base + (size_t)co * 32 + qd * 8 + (w & 1) * 4) = pk.u;
    }
  }
}

// ---------------- k4: flash attention, K in LDS, V via L1 ------------------
// 512 blocks = 32 i-tiles(128 rows) x 16 (b,js); 4 waves x 32 query rows.
// K double-buffered via glds (one barrier/iter). V-frags read straight from
// global vS (all 4 waves hit the same addresses -> L1 broadcast), issued in
// 4 groups of 4 to bound register pressure. P stays in registers.
__global__ __launch_bounds__(256, 2) void k_attn(const bf16* __restrict__ qT,
    const bf16* __restrict__ kS, const bf16* __restrict__ vS,
    bf16* __restrict__ Op0, bf16* __restrict__ Op1, float* __restrict__ Lp) {
  __shared__ bf16 Kb[2][8192];    // 16 KB each, pre-swizzled granules

  const int bjs = blockIdx.x & 15;          // same (b,js) -> same XCD (%8)
  const int itb = blockIdx.x >> 4;          // 0..31
  const int b = bjs >> 1, js = bjs & 1;
  const int i0 = itb * 128;
  const int tid = threadIdx.x, w = tid >> 6, lane = tid & 63;
  const int li = lane & 15, qd = lane >> 4;

  const bf16* kS_b = kS + (size_t)b * 1048576 + (size_t)js * 524288;
  const bf16* vS_b = vS + (size_t)b * 1048576 + (size_t)js * 524288
                   + li * 32 + qd * 8;      // + jc*8192 + ct*512

  bf16x8 qf[2][8];
  #pragma unroll
  for (int it = 0; it < 2; ++it) {
    const bf16* qp = qT + ((size_t)b * NSP + i0 + w * 32 + it * 16 + li) * NCH + qd * 8;
    #pragma unroll
    for (int kc = 0; kc < 8; ++kc) qf[it][kc] = *(const bf16x8*)(qp + kc * 32);
  }

  f32x4 Oa[2][16];
  #pragma unroll
  for (int it = 0; it < 2; ++it)
    #pragma unroll
    for (int t = 0; t < 16; ++t) Oa[it][t] = (f32x4){0.f, 0.f, 0.f, 0.f};
  float lacc[2] = {0.f, 0.f};

  // preamble: stage K tile 0
  #pragma unroll
  for (int p = 0; p < 4; ++p)
    glds16(kS_b + (size_t)(w * 256 + p * 64 + lane) * 8, &Kb[0][(w * 256 + p * 64) * 8]);

  for (int jc = 0; jc < 64; ++jc) {
    const int cur = jc & 1;
    __syncthreads();                         // drains K(jc) glds; prev reads done
    if (jc < 63) {                           // prefetch K(jc+1), shadow = compute
      const bf16* kt = kS_b + (size_t)(jc + 1) * 8192;
      #pragma unroll
      for (int p = 0; p < 4; ++p)
        glds16(kt + (size_t)(w * 256 + p * 64 + lane) * 8, &Kb[cur ^ 1][(w * 256 + p * 64) * 8]);
    }
    const bf16* vt = vS_b + (size_t)jc * 8192;

    bf16x8 vf0[4], vf1[4], vf2[4], vf3[4];
    #pragma unroll
    for (int u = 0; u < 4; ++u) vf0[u] = *(const bf16x8*)(vt + u * 512);

    // S^T = (K Q^T): lane holds S[i=li][j=jt*16+qd*4+r]
    const bf16* Kc = Kb[cur];
    f32x4 S[2][2];
    S[0][0] = (f32x4){0.f,0.f,0.f,0.f}; S[0][1] = (f32x4){0.f,0.f,0.f,0.f};
    S[1][0] = (f32x4){0.f,0.f,0.f,0.f}; S[1][1] = (f32x4){0.f,0.f,0.f,0.f};
    #pragma unroll
    for (int kc = 0; kc < 8; ++kc) {
      int pb = (kc * 4 + qd) ^ (li & 7);
      bf16x8 kf = *(const bf16x8*)(Kc + li * 256 + pb * 8);
      S[0][0] = __builtin_amdgcn_mfma_f32_16x16x32_bf16(kf, qf[0][kc], S[0][0], 0, 0, 0);
      S[1][0] = __builtin_amdgcn_mfma_f32_16x16x32_bf16(kf, qf[1][kc], S[1][0], 0, 0, 0);
    }
    #pragma unroll
    for (int u = 0; u < 4; ++u) vf1[u] = *(const bf16x8*)(vt + (4 + u) * 512);
    #pragma unroll
    for (int kc = 0; kc < 8; ++kc) {
      int pb = (kc * 4 + qd) ^ (li & 7);
      bf16x8 kf = *(const bf16x8*)(Kc + (16 + li) * 256 + pb * 8);
      S[0][1] = __builtin_amdgcn_mfma_f32_16x16x32_bf16(kf, qf[0][kc], S[0][1], 0, 0, 0);
      S[1][1] = __builtin_amdgcn_mfma_f32_16x16x32_bf16(kf, qf[1][kc], S[1][1], 0, 0, 0);
    }
    #pragma unroll
    for (int u = 0; u < 4; ++u) vf2[u] = *(const bf16x8*)(vt + (8 + u) * 512);

    // P = exp(S-8) in-register; pf[it] is the PV B-operand (element t -> j =
    // qd*4 + (t&3) + 16*(t>>2)), matching vS's plain granule layout.
    bf16x8 pf[2];
    #pragma unroll
    for (int it = 0; it < 2; ++it)
      #pragma unroll
      for (int jt = 0; jt < 2; ++jt)
        #pragma unroll
        for (int r = 0; r < 4; ++r) {
          float e = __expf(S[it][jt][r] - 8.f);
          lacc[it] += e;
          pf[it][jt * 4 + r] = (bf16)e;
        }
    #pragma unroll
    for (int u = 0; u < 4; ++u) vf3[u] = *(const bf16x8*)(vt + (12 + u) * 512);

    // O += V P^T: D[m=c][n=i]; V-frags from L1, each feeds both i-tiles
    #pragma unroll
    for (int u = 0; u < 4; ++u) {
      Oa[0][u] = __builtin_amdgcn_mfma_f32_16x16x32_bf16(vf0[u], pf[0], Oa[0][u], 0, 0, 0);
      Oa[1][u] = __builtin_amdgcn_mfma_f32_16x16x32_bf16(vf0[u], pf[1], Oa[1][u], 0, 0, 0);
    }
    #pragma unroll
    for (int u = 0; u < 4; ++u) {
      Oa[0][4 + u] = __builtin_amdgcn_mfma_f32_16x16x32_bf16(vf1[u], pf[0], Oa[0][4 + u], 0, 0, 0);
      Oa[1][4 + u] = __builtin_amdgcn_mfma_f32_16x16x32_bf16(vf1[u], pf[1], Oa[1][4 + u], 0, 0, 0);
    }
    #pragma unroll
    for (int u = 0; u < 4; ++u) {
      Oa[0][8 + u] = __builtin_amdgcn_mfma_f32_16x16x32_bf16(vf2[u], pf[0], Oa[0][8 + u], 0, 0, 0);
      Oa[1][8 + u] = __builtin_amdgcn_mfma_f32_16x16x32_bf16(vf2[u], pf[1], Oa[1][8 + u], 0, 0, 0);
    }
    #pragma unroll
    for (int u = 0; u < 4; ++u) {
      Oa[0][12 + u] = __builtin_amdgcn_mfma_f32_16x16x32_bf16(vf3[u], pf[0], Oa[0][12 + u], 0, 0, 0);
      Oa[1][12 + u] = __builtin_amdgcn_mfma_f32_16x16x32_bf16(vf3[u], pf[1], Oa[1][12 + u], 0, 0, 0);
    }
  }

  // epilogue: l is indexed by i=li -> reduce across qd groups only
  float lfull[2], linv[2];
  #pragma unroll
  for (int it = 0; it < 2; ++it) {
    float v = lacc[it];
    v += __shfl_xor(v, 16);
    v += __shfl_xor(v, 32);
    lfull[it] = v;
    linv[it] = 1.f / v;
  }

  bf16* Op = js ? Op1 : Op0;
  #pragma unroll
  for (int it = 0; it < 2; ++it) {
    bf16* op = Op + ((size_t)b * NSP + i0 + w * 32 + it * 16 + li) * NCH;
    #pragma unroll
    for (int ct = 0; ct < 16; ++ct) {
      union { bf16 h[4]; uint2 u; } pk;
      pk.h[0] = (bf16)(Oa[it][ct][0] * linv[it]);
      pk.h[1] = (bf16)(Oa[it][ct][1] * linv[it]);
      pk.h[2] = (bf16)(Oa[it][ct][2] * linv[it]);
      pk.h[3] = (bf16)(Oa[it][ct][3] * linv[it]);
      *(uint2*)(op + ct * 16 + qd * 4) = pk.u;
    }
  }
  if (qd == 0) {
    float* lp = Lp + js * 32768 + b * 4096 + i0 + w * 32;
    #pragma unroll
    for (int it = 0; it < 2; ++it) lp[it * 16 + li] = lfull[it];
  }
}

// ---------------- k5: out = x + wo @ blend(Op0,Op1) + bo -------------------
__global__ __launch_bounds__(256, 4) void k_out(const bf16* __restrict__ Op0,
    const bf16* __restrict__ Op1, const float* __restrict__ Lp,
    const bf16* __restrict__ wo, const float* __restrict__ bo,
    const float* __restrict__ x, float* __restrict__ out) {
  const int b  = blockIdx.x >> 7;
  const int i0 = ((blockIdx.x >> 1) & 63) * 64;
  const int ch = blockIdx.x & 1;
  const int tid = threadIdx.x, w = tid >> 6, lane = tid & 63;
  const int li = lane & 15, qd = lane >> 4;
  const int cb0 = ch * 128 + w * 32;

  float w0[4], w1[4];
  #pragma unroll
  for (int nt = 0; nt < 4; ++nt) {
    int i = b * 4096 + i0 + nt * 16 + li;
    float l0 = Lp[i], l1 = Lp[32768 + i];
    float inv = 1.f / (l0 + l1);
    w0[nt] = l0 * inv; w1[nt] = l1 * inv;
  }

  f32x4 acc[8];
  #pragma unroll
  for (int t = 0; t < 8; ++t) acc[t] = (f32x4){0.f, 0.f, 0.f, 0.f};
  for (int kc = 0; kc < 8; ++kc) {
    bf16x8 ab[4];
    #pragma unroll
    for (int nt = 0; nt < 4; ++nt) {
      size_t off = ((size_t)b * NSP + i0 + nt * 16 + li) * NCH + kc * 32 + qd * 8;
      bf16x8 a0 = *(const bf16x8*)(Op0 + off);
      bf16x8 a1 = *(const bf16x8*)(Op1 + off);
      #pragma unroll
      for (int e = 0; e < 8; ++e)
        ab[nt][e] = (bf16)(w0[nt] * (float)a0[e] + w1[nt] * (float)a1[e]);
    }
    #pragma unroll
    for (int mt = 0; mt < 2; ++mt) {
      bf16x8 wf = *(const bf16x8*)(wo + (size_t)(cb0 + mt * 16 + li) * NCH + kc * 32 + qd * 8);
      #pragma unroll
      for (int nt = 0; nt < 4; ++nt)
        acc[mt * 4 + nt] = __builtin_amdgcn_mfma_f32_16x16x32_bf16(wf, ab[nt], acc[mt * 4 + nt], 0, 0, 0);
    }
  }
  #pragma unroll
  for (int mt = 0; mt < 2; ++mt) {
    #pragma unroll
    for (int r = 0; r < 4; ++r) {
      int co = cb0 + mt * 16 + qd * 4 + r;
      float bb = bo[co];
      #pragma unroll
      for (int nt = 0; nt < 4; ++nt) {
        size_t idx = ((size_t)b * NCH + co) * NSP + i0 + nt * 16 + li;
        out[idx] = acc[mt * 4 + nt][r] + bb + x[idx];
      }
    }
  }
}

// ---------------- host ------------------------------------------------------
extern "C" void kernel_launch(void* const* d_in, const int* in_sizes, int n_in,
                              void* d_out, int out_size, void* d_ws, size_t ws_size,
                              hipStream_t stream) {
  (void)in_sizes; (void)n_in; (void)out_size; (void)ws_size;
  const float* x   = (const float*)d_in[0];
  const float* gsc = (const float*)d_in[1];
  const float* gbi = (const float*)d_in[2];
  const float* wq  = (const float*)d_in[3];
  const float* bq  = (const float*)d_in[4];
  const float* wk  = (const float*)d_in[5];
  const float* bk  = (const float*)d_in[6];
  const float* wv  = (const float*)d_in[7];
  const float* bv  = (const float*)d_in[8];
  const float* wo  = (const float*)d_in[9];
  const float* bo  = (const float*)d_in[10];

  char* ws = (char*)d_ws;
  const size_t MB16 = 16777216u;
  bf16*   wbf   = (bf16*)(ws);                         // 512 KB
  float*  stats = (float*)(ws + 524288);               // 512 B
  float2* part  = (float2*)(ws + 528384);              // 4 KB
  float*  Lp    = (float*)(ws + 655360);               // 256 KB
  bf16*   hnT   = (bf16*)(ws + (1u << 20));            // 16 MB; reused as Op0
  bf16*   qT    = (bf16*)(ws + (1u << 20) + 1 * MB16);
  bf16*   kS    = (bf16*)(ws + (1u << 20) + 2 * MB16); // swizzled K tiles
  bf16*   vS    = (bf16*)(ws + (1u << 20) + 3 * MB16); // plain V tiles
  bf16*   Op1   = (bf16*)(ws + (1u << 20) + 4 * MB16);
  bf16*   Op0   = hnT;   // hnT dead after k_qkv
  float*  out   = (float*)d_out;

  k_prep    <<<1536, 256, 0, stream>>>(x, wq, wk, wv, wo, wbf, part);
  k_gnstats2<<<   1,  64, 0, stream>>>(part, stats);
  k_gnapply <<<2048, 256, 0, stream>>>(x, stats, gsc, gbi, hnT);
  k_qkv     <<< 512, 256, 0, stream>>>(hnT, wbf, bq, bk, bv, qT, kS, vS);
  k_attn    <<< 512, 256, 0, stream>>>(qT, kS, vS, Op0, Op1, Lp);
  k_out     <<<1024, 256, 0, stream>>>(Op0, Op1, Lp, wbf + 3ull * 65536, bo, x, out);
}

// Round 6
// 370.186 us; speedup vs baseline: 1.4883x; 1.4883x over previous
//
#include <hip/hip_runtime.h>

typedef __bf16 bf16;
typedef __bf16 bf16x8 __attribute__((ext_vector_type(8)));
typedef float  f32x4  __attribute__((ext_vector_type(4)));

#define NSP 4096   // h*w
#define NCH 256    // channels
#define NB  8      // batch

// global(16B per lane) -> LDS at wave-uniform base + lane*16
static __device__ __forceinline__ void glds16(const bf16* g, bf16* l) {
  __builtin_amdgcn_global_load_lds(
      (const __attribute__((address_space(1))) unsigned int*)g,
      (__attribute__((address_space(3))) unsigned int*)l, 16, 0, 0);
}

// ---------------- k_prep: GN partial sums (blocks 0..511) + weight cvt ----
__global__ __launch_bounds__(256) void k_prep(const float* __restrict__ x,
    const float* __restrict__ wq, const float* __restrict__ wk,
    const float* __restrict__ wv, const float* __restrict__ wo,
    bf16* __restrict__ wbf, float2* __restrict__ part) {
  if (blockIdx.x < 512) {                       // GN stats: 64 bg * 8 seg
    int blk = blockIdx.x;
    int bg = blk >> 3, seg = blk & 7;
    const float4* p = (const float4*)(x + (size_t)bg * 131072 + seg * 16384);
    float s = 0.f, s2 = 0.f;
    for (int i = threadIdx.x; i < 4096; i += 256) {
      float4 v = p[i];
      s  += v.x + v.y + v.z + v.w;
      s2 += v.x*v.x + v.y*v.y + v.z*v.z + v.w*v.w;
    }
    for (int off = 1; off < 64; off <<= 1) {
      s  += __shfl_xor(s, off);
      s2 += __shfl_xor(s2, off);
    }
    __shared__ float a1[4], a2[4];
    int w = threadIdx.x >> 6, lane = threadIdx.x & 63;
    if (lane == 0) { a1[w] = s; a2[w] = s2; }
    __syncthreads();
    if (threadIdx.x == 0)
      part[blk] = make_float2(a1[0]+a1[1]+a1[2]+a1[3], a2[0]+a2[1]+a2[2]+a2[3]);
  } else {                                      // weight fp32->bf16
    int g = (blockIdx.x - 512) * 256 + threadIdx.x;   // 0..262143
    int m = g >> 16, idx = g & 65535;
    const float* src = (m == 0) ? wq : (m == 1) ? wk : (m == 2) ? wv : wo;
    float sc = (m == 0) ? 0.0625f : 1.0f;
    wbf[g] = (bf16)(src[idx] * sc);
  }
}

// ---------------- k1b: finalize stats --------------------------------------
__global__ __launch_bounds__(64) void k_gnstats2(const float2* __restrict__ part,
                                                 float* __restrict__ stats) {
  int bg = threadIdx.x;                         // 64
  float s = 0.f, s2 = 0.f;
  #pragma unroll
  for (int k = 0; k < 8; ++k) {
    float2 v = part[bg * 8 + k];
    s += v.x; s2 += v.y;
  }
  float mean = s * (1.f / 131072.f);
  float var  = s2 * (1.f / 131072.f) - mean * mean;
  stats[bg * 2]     = mean;
  stats[bg * 2 + 1] = rsqrtf(var + 1e-6f);
}

// ---------------- k3: fused GN + QKV ---------------------------------------
// 512 blocks. Per block: GN-normalize + transpose a 64i x 256c tile of x
// into hnS (granule-swizzled g' = g ^ (i&7)) via chunked LDS transpose,
// then the q/k/v MFMA passes.
// q: qT[b][i][c].  k: kS pre-swizzled K tiles (granule cb ^ (j&7)).
// v: vS pre-swizzled V tiles (256c x 32j); granule g of row c holds
// j in {4g+t, 16+4g+t}, placed at pg = g ^ ((c>>1)&3).
__global__ __launch_bounds__(256, 3) void k_qkv(const float* __restrict__ x,
    const float* __restrict__ stats, const float* __restrict__ gsc,
    const float* __restrict__ gbi, const bf16* __restrict__ wbf,
    const float* __restrict__ bq, const float* __restrict__ bk,
    const float* __restrict__ bv,
    bf16* __restrict__ qT, bf16* __restrict__ kS, bf16* __restrict__ vS) {
  __shared__ float T[64][65];                   // 16.6 KB transpose buffer
  __shared__ bf16 hnS[64 * 256];                // 32 KB
  const int b  = blockIdx.x >> 6;
  const int i0 = (blockIdx.x & 63) * 64;
  const int tid = threadIdx.x, w = tid >> 6, lane = tid & 63;
  const int li = lane & 15, qd = lane >> 4;

  // --- GN apply + transpose, 4 chunks of 64 channels ---
  for (int ct = 0; ct < 4; ++ct) {
    if (ct) __syncthreads();                    // T reuse
    #pragma unroll 4
    for (int p = 0; p < 16; ++p) {
      int cc = p * 4 + (tid >> 6), ii = tid & 63;
      int c = ct * 64 + cc;
      float mean = stats[(b * 8 + (c >> 5)) * 2];
      float rstd = stats[(b * 8 + (c >> 5)) * 2 + 1];
      float v = x[((size_t)b * NCH + c) * NSP + i0 + ii];
      T[cc][ii] = (v - mean) * rstd * gsc[c] + gbi[c];
    }
    __syncthreads();
    #pragma unroll
    for (int h = 0; h < 2; ++h) {               // 512 octets / 256 threads
      int oid = h * 256 + tid;
      int g8 = oid & 7;                         // c-octet within chunk
      int i  = oid >> 3;                        // 0..63
      bf16x8 pk;
      #pragma unroll
      for (int e = 0; e < 8; ++e) pk[e] = (bf16)T[g8 * 8 + e][i];
      int g = ct * 8 + g8;
      *(bf16x8*)(&hnS[i * 256 + (g ^ (i & 7)) * 8]) = pk;
    }
  }
  __syncthreads();

  // --- q/k passes: D[m=co][n=i], A = W rows(co), B = hn rows(i) ---
  #pragma unroll 1
  for (int pass = 0; pass < 2; ++pass) {
    const bf16* W = wbf + (size_t)pass * 65536;
    f32x4 acc[16];
    #pragma unroll
    for (int t = 0; t < 16; ++t) acc[t] = (f32x4){0.f, 0.f, 0.f, 0.f};
    for (int kc = 0; kc < 8; ++kc) {
      bf16x8 hb[4];
      #pragma unroll
      for (int nt = 0; nt < 4; ++nt)
        hb[nt] = *(const bf16x8*)(&hnS[(nt * 16 + li) * 256 + ((kc * 4 + qd) ^ (li & 7)) * 8]);
      #pragma unroll
      for (int mt = 0; mt < 4; ++mt) {
        bf16x8 wf = *(const bf16x8*)(W + (size_t)(w * 64 + mt * 16 + li) * NCH + kc * 32 + qd * 8);
        #pragma unroll
        for (int nt = 0; nt < 4; ++nt)
          acc[mt * 4 + nt] = __builtin_amdgcn_mfma_f32_16x16x32_bf16(wf, hb[nt], acc[mt * 4 + nt], 0, 0, 0);
      }
    }
    if (pass == 0) {
      bf16* out = qT + ((size_t)b * NSP + i0) * NCH;
      #pragma unroll
      for (int mt = 0; mt < 4; ++mt) {
        float bb[4];
        #pragma unroll
        for (int r = 0; r < 4; ++r) bb[r] = bq[w * 64 + mt * 16 + qd * 4 + r] * 0.0625f;
        #pragma unroll
        for (int nt = 0; nt < 4; ++nt) {
          union { bf16 h[4]; uint2 u; } pk;
          #pragma unroll
          for (int r = 0; r < 4; ++r) pk.h[r] = (bf16)(acc[mt * 4 + nt][r] + bb[r]);
          *(uint2*)(out + (size_t)(nt * 16 + li) * NCH + w * 64 + mt * 16 + qd * 4) = pk.u;
        }
      }
    } else {
      #pragma unroll
      for (int mt = 0; mt < 4; ++mt) {
        float bb[4];
        #pragma unroll
        for (int r = 0; r < 4; ++r) bb[r] = bk[w * 64 + mt * 16 + qd * 4 + r];
        int cb = w * 8 + mt * 2 + (qd >> 1);
        #pragma unroll
        for (int nt = 0; nt < 4; ++nt) {
          int jloc = nt * 16 + li;
          size_t base = (size_t)b * 1048576 + (size_t)((i0 + jloc) >> 5) * 8192;
          int r32 = jloc & 31;
          union { bf16 h[4]; uint2 u; } pk;
          #pragma unroll
          for (int r = 0; r < 4; ++r) pk.h[r] = (bf16)(acc[mt * 4 + nt][r] + bb[r]);
          *(uint2*)(kS + base + r32 * 256 + (cb ^ (r32 & 7)) * 8 + (qd & 1) * 4) = pk.u;
        }
      }
    }
  }

  // --- v pass: D[m=j][n=co], A = hn rows(j), B = Wv rows(co) ---
  {
    const bf16* W = wbf + 2ull * 65536;
    f32x4 acc[16];
    #pragma unroll
    for (int t = 0; t < 16; ++t) acc[t] = (f32x4){0.f, 0.f, 0.f, 0.f};
    for (int kc = 0; kc < 8; ++kc) {
      bf16x8 hb = *(const bf16x8*)(&hnS[(w * 16 + li) * 256 + ((kc * 4 + qd) ^ (li & 7)) * 8]);
      #pragma unroll
      for (int ct = 0; ct < 16; ++ct) {
        bf16x8 wf = *(const bf16x8*)(W + (size_t)(ct * 16 + li) * NCH + kc * 32 + qd * 8);
        acc[ct] = __builtin_amdgcn_mfma_f32_16x16x32_bf16(hb, wf, acc[ct], 0, 0, 0);
      }
    }
    // j = w*16 + qd*4 + r ; granule g = qd, half hi = w&1, element t = r
    int jloc = w * 16 + qd * 4;
    size_t base = (size_t)b * 1048576 + (size_t)((i0 + jloc) >> 5) * 8192;
    int hi = (jloc >> 4) & 1;
    #pragma unroll
    for (int ct = 0; ct < 16; ++ct) {
      int co = ct * 16 + li;
      float bb = bv[co];
      int pg = qd ^ ((co >> 1) & 3);
      union { bf16 h[4]; uint2 u; } pk;
      #pragma unroll
      for (int r = 0; r < 4; ++r) pk.h[r] = (bf16)(acc[ct][r] + bb);
      *(uint2*)(vS + base + (size_t)(co * 4 + pg) * 8 + hi * 4) = pk.u;
    }
  }
}

// ---------------- k4: flash attention, K+V glds double-buffered ------------
// 512 blocks = 32 i-tiles(128 rows) x 16 (b,js); 4 waves x 32 query rows.
// One barrier per iteration: glds(jc+1) writes the jc-1 buffers, which the
// barrier proves fully read; vmcnt(0) before the next barrier lands after a
// full compute-phase shadow. P stays in registers (S^T trick).
__global__ __launch_bounds__(256, 2) void k_attn(const bf16* __restrict__ qT,
    const bf16* __restrict__ kS, const bf16* __restrict__ vS,
    bf16* __restrict__ Op0, bf16* __restrict__ Op1, float* __restrict__ Lp) {
  __shared__ bf16 Kb[2][8192];    // 16 KB each, pre-swizzled granules
  __shared__ bf16 Vb[2][8192];    // 16 KB each, pre-swizzled granules

  const int bjs = blockIdx.x & 15;          // same (b,js) -> same XCD (%8)
  const int itb = blockIdx.x >> 4;          // 0..31
  const int b = bjs >> 1, js = bjs & 1;
  const int i0 = itb * 128;
  const int tid = threadIdx.x, w = tid >> 6, lane = tid & 63;
  const int li = lane & 15, qd = lane >> 4;

  const bf16* kS_b = kS + (size_t)b * 1048576 + (size_t)js * 524288;
  const bf16* vS_b = vS + (size_t)b * 1048576 + (size_t)js * 524288;

  bf16x8 qf[2][8];
  #pragma unroll
  for (int it = 0; it < 2; ++it) {
    const bf16* qp = qT + ((size_t)b * NSP + i0 + w * 32 + it * 16 + li) * NCH + qd * 8;
    #pragma unroll
    for (int kc = 0; kc < 8; ++kc) qf[it][kc] = *(const bf16x8*)(qp + kc * 32);
  }

  f32x4 Oa[2][16];
  #pragma unroll
  for (int it = 0; it < 2; ++it)
    #pragma unroll
    for (int t = 0; t < 16; ++t) Oa[it][t] = (f32x4){0.f, 0.f, 0.f, 0.f};
  float lacc[2] = {0.f, 0.f};

  // preamble: stage K,V tile 0
  #pragma unroll
  for (int p = 0; p < 4; ++p)
    glds16(kS_b + (size_t)(w * 256 + p * 64 + lane) * 8, &Kb[0][(w * 256 + p * 64) * 8]);
  #pragma unroll
  for (int p = 0; p < 4; ++p)
    glds16(vS_b + (size_t)(w * 256 + p * 64 + lane) * 8, &Vb[0][(w * 256 + p * 64) * 8]);

  const int pgv = qd ^ ((li >> 1) & 3);      // V granule swizzle (read side)

  for (int jc = 0; jc < 64; ++jc) {
    const int cur = jc & 1;
    __syncthreads();                         // glds(jc) landed; jc-1 reads done
    if (jc < 63) {                           // prefetch jc+1 into jc-1 buffers
      const bf16* kt = kS_b + (size_t)(jc + 1) * 8192;
      const bf16* vt = vS_b + (size_t)(jc + 1) * 8192;
      #pragma unroll
      for (int p = 0; p < 4; ++p)
        glds16(kt + (size_t)(w * 256 + p * 64 + lane) * 8, &Kb[cur ^ 1][(w * 256 + p * 64) * 8]);
      #pragma unroll
      for (int p = 0; p < 4; ++p)
        glds16(vt + (size_t)(w * 256 + p * 64 + lane) * 8, &Vb[cur ^ 1][(w * 256 + p * 64) * 8]);
    }

    // S^T = (K Q^T): lane holds S[i=li][j=jt*16+qd*4+r]
    const bf16* Kc = Kb[cur];
    f32x4 S[2][2];
    S[0][0] = (f32x4){0.f,0.f,0.f,0.f}; S[0][1] = (f32x4){0.f,0.f,0.f,0.f};
    S[1][0] = (f32x4){0.f,0.f,0.f,0.f}; S[1][1] = (f32x4){0.f,0.f,0.f,0.f};
    #pragma unroll
    for (int jt = 0; jt < 2; ++jt) {
      #pragma unroll
      for (int kc = 0; kc < 8; ++kc) {
        int pb = (kc * 4 + qd) ^ (li & 7);
        bf16x8 kf = *(const bf16x8*)(Kc + (jt * 16 + li) * 256 + pb * 8);
        S[0][jt] = __builtin_amdgcn_mfma_f32_16x16x32_bf16(kf, qf[0][kc], S[0][jt], 0, 0, 0);
        S[1][jt] = __builtin_amdgcn_mfma_f32_16x16x32_bf16(kf, qf[1][kc], S[1][jt], 0, 0, 0);
      }
    }

    // P = exp(S-8) in-register; pf[it] element jt*4+r -> j = 16jt + 4qd + r,
    // matching vS granule g=qd layout {4g+t, 16+4g+t}.
    bf16x8 pf[2];
    #pragma unroll
    for (int it = 0; it < 2; ++it)
      #pragma unroll
      for (int jt = 0; jt < 2; ++jt)
        #pragma unroll
        for (int r = 0; r < 4; ++r) {
          float e = __expf(S[it][jt][r] - 8.f);
          lacc[it] += e;
          pf[it][jt * 4 + r] = (bf16)e;
        }

    // O += V P^T: D[m=c][n=i]; one b128 V-frag per ct feeds both i-tiles
    const bf16* Vc = Vb[cur];
    #pragma unroll
    for (int ct = 0; ct < 16; ++ct) {
      bf16x8 vf = *(const bf16x8*)(Vc + (size_t)(ct * 16 + li) * 32 + pgv * 8);
      Oa[0][ct] = __builtin_amdgcn_mfma_f32_16x16x32_bf16(vf, pf[0], Oa[0][ct], 0, 0, 0);
      Oa[1][ct] = __builtin_amdgcn_mfma_f32_16x16x32_bf16(vf, pf[1], Oa[1][ct], 0, 0, 0);
    }
  }

  // epilogue: l is indexed by i=li -> reduce across qd groups only
  float lfull[2], linv[2];
  #pragma unroll
  for (int it = 0; it < 2; ++it) {
    float v = lacc[it];
    v += __shfl_xor(v, 16);
    v += __shfl_xor(v, 32);
    lfull[it] = v;
    linv[it] = 1.f / v;
  }

  bf16* Op = js ? Op1 : Op0;
  #pragma unroll
  for (int it = 0; it < 2; ++it) {
    bf16* op = Op + ((size_t)b * NSP + i0 + w * 32 + it * 16 + li) * NCH;
    #pragma unroll
    for (int ct = 0; ct < 16; ++ct) {
      union { bf16 h[4]; uint2 u; } pk;
      pk.h[0] = (bf16)(Oa[it][ct][0] * linv[it]);
      pk.h[1] = (bf16)(Oa[it][ct][1] * linv[it]);
      pk.h[2] = (bf16)(Oa[it][ct][2] * linv[it]);
      pk.h[3] = (bf16)(Oa[it][ct][3] * linv[it]);
      *(uint2*)(op + ct * 16 + qd * 4) = pk.u;
    }
  }
  if (qd == 0) {
    float* lp = Lp + js * 32768 + b * 4096 + i0 + w * 32;
    #pragma unroll
    for (int it = 0; it < 2; ++it) lp[it * 16 + li] = lfull[it];
  }
}

// ---------------- k5: out = x + wo @ blend(Op0,Op1) + bo -------------------
__global__ __launch_bounds__(256, 4) void k_out(const bf16* __restrict__ Op0,
    const bf16* __restrict__ Op1, const float* __restrict__ Lp,
    const bf16* __restrict__ wo, const float* __restrict__ bo,
    const float* __restrict__ x, float* __restrict__ out) {
  const int b  = blockIdx.x >> 7;
  const int i0 = ((blockIdx.x >> 1) & 63) * 64;
  const int ch = blockIdx.x & 1;
  const int tid = threadIdx.x, w = tid >> 6, lane = tid & 63;
  const int li = lane & 15, qd = lane >> 4;
  const int cb0 = ch * 128 + w * 32;

  float w0[4], w1[4];
  #pragma unroll
  for (int nt = 0; nt < 4; ++nt) {
    int i = b * 4096 + i0 + nt * 16 + li;
    float l0 = Lp[i], l1 = Lp[32768 + i];
    float inv = 1.f / (l0 + l1);
    w0[nt] = l0 * inv; w1[nt] = l1 * inv;
  }

  f32x4 acc[8];
  #pragma unroll
  for (int t = 0; t < 8; ++t) acc[t] = (f32x4){0.f, 0.f, 0.f, 0.f};
  for (int kc = 0; kc < 8; ++kc) {
    bf16x8 ab[4];
    #pragma unroll
    for (int nt = 0; nt < 4; ++nt) {
      size_t off = ((size_t)b * NSP + i0 + nt * 16 + li) * NCH + kc * 32 + qd * 8;
      bf16x8 a0 = *(const bf16x8*)(Op0 + off);
      bf16x8 a1 = *(const bf16x8*)(Op1 + off);
      #pragma unroll
      for (int e = 0; e < 8; ++e)
        ab[nt][e] = (bf16)(w0[nt] * (float)a0[e] + w1[nt] * (float)a1[e]);
    }
    #pragma unroll
    for (int mt = 0; mt < 2; ++mt) {
      bf16x8 wf = *(const bf16x8*)(wo + (size_t)(cb0 + mt * 16 + li) * NCH + kc * 32 + qd * 8);
      #pragma unroll
      for (int nt = 0; nt < 4; ++nt)
        acc[mt * 4 + nt] = __builtin_amdgcn_mfma_f32_16x16x32_bf16(wf, ab[nt], acc[mt * 4 + nt], 0, 0, 0);
    }
  }
  #pragma unroll
  for (int mt = 0; mt < 2; ++mt) {
    #pragma unroll
    for (int r = 0; r < 4; ++r) {
      int co = cb0 + mt * 16 + qd * 4 + r;
      float bb = bo[co];
      #pragma unroll
      for (int nt = 0; nt < 4; ++nt) {
        size_t idx = ((size_t)b * NCH + co) * NSP + i0 + nt * 16 + li;
        out[idx] = acc[mt * 4 + nt][r] + bb + x[idx];
      }
    }
  }
}

// ---------------- host ------------------------------------------------------
extern "C" void kernel_launch(void* const* d_in, const int* in_sizes, int n_in,
                              void* d_out, int out_size, void* d_ws, size_t ws_size,
                              hipStream_t stream) {
  (void)in_sizes; (void)n_in; (void)out_size; (void)ws_size;
  const float* x   = (const float*)d_in[0];
  const float* gsc = (const float*)d_in[1];
  const float* gbi = (const float*)d_in[2];
  const float* wq  = (const float*)d_in[3];
  const float* bq  = (const float*)d_in[4];
  const float* wk  = (const float*)d_in[5];
  const float* bk  = (const float*)d_in[6];
  const float* wv  = (const float*)d_in[7];
  const float* bv  = (const float*)d_in[8];
  const float* wo  = (const float*)d_in[9];
  const float* bo  = (const float*)d_in[10];

  char* ws = (char*)d_ws;
  const size_t MB16 = 16777216u;
  bf16*   wbf   = (bf16*)(ws);                         // 512 KB
  float*  stats = (float*)(ws + 524288);               // 512 B
  float2* part  = (float2*)(ws + 528384);              // 4 KB
  float*  Lp    = (float*)(ws + 655360);               // 256 KB
  bf16*   Op0   = (bf16*)(ws + (1u << 20));            // 16 MB
  bf16*   qT    = (bf16*)(ws + (1u << 20) + 1 * MB16);
  bf16*   kS    = (bf16*)(ws + (1u << 20) + 2 * MB16); // swizzled K tiles
  bf16*   vS    = (bf16*)(ws + (1u << 20) + 3 * MB16); // swizzled V tiles
  bf16*   Op1   = (bf16*)(ws + (1u << 20) + 4 * MB16);
  float*  out   = (float*)d_out;

  k_prep    <<<1536, 256, 0, stream>>>(x, wq, wk, wv, wo, wbf, part);
  k_gnstats2<<<   1,  64, 0, stream>>>(part, stats);
  k_qkv     <<< 512, 256, 0, stream>>>(x, stats, gsc, gbi, wbf, bq, bk, bv, qT, kS, vS);
  k_attn    <<< 512, 256, 0, stream>>>(qT, kS, vS, Op0, Op1, Lp);
  k_out     <<<1024, 256, 0, stream>>>(Op0, Op1, Lp, wbf + 3ull * 65536, bo, x, out);
}